// Round 3
// baseline (364.553 us; speedup 1.0000x reference)
//
#include <hip/hip_runtime.h>
#include <hip/hip_bf16.h>

// SRU cell, fp32 in / fp32 out (internal bf16 MFMA GEMM).
// u = x@W; then L-sequential scan parallel over B*d.
// L=1024, B=32, d=512. M=L*B=32768, K=512, N=3d=1536.
// ws: xb (bf16, 32MB) | Wt (bf16 [N][K], 1.5MB) | u (bf16 [M][N], 96MB)

typedef __attribute__((ext_vector_type(8))) __bf16 bf16x8;
typedef __attribute__((ext_vector_type(4))) __bf16 bf16x4;
typedef __attribute__((ext_vector_type(4))) float floatx4;

#define GK 512
#define GN 1536

// ---- convert x (fp32) -> bf16, 4 elems/thread --------------------------------
__global__ __launch_bounds__(256) void cvt_x(const float4* __restrict__ in,
                                             bf16x4* __restrict__ out) {
  int i = blockIdx.x * 256 + threadIdx.x;  // 4,194,304 threads exactly
  float4 v = in[i];
  bf16x4 o = {(__bf16)v.x, (__bf16)v.y, (__bf16)v.z, (__bf16)v.w};
  out[i] = o;
}

// ---- convert + transpose weight: W[K][N] fp32 -> Wt[N][K] bf16 ---------------
__global__ __launch_bounds__(256) void cvt_w(const float* __restrict__ w,
                                             __bf16* __restrict__ wt) {
  int idx = blockIdx.x * 256 + threadIdx.x;  // 0..786431 = n*512+k
  int n = idx >> 9, k = idx & 511;
  wt[idx] = (__bf16)w[(size_t)k * GN + n];  // strided reads; 3MB, L2 absorbs
}

// ---- GEMM: C[M][N] = A[M][K] * Wt[N][K]^T, bf16 in, bf16 out -----------------
// 128x128 block tile, BK=32, 4 waves each 64x64 (4x4 of 16x16x32 MFMA).
// global_load_lds width=16 staging; XOR swizzle keeps ds_read_b128 <=2-way.
__global__ __launch_bounds__(256) void gemm_kernel(const __bf16* __restrict__ A,
                                                   const __bf16* __restrict__ Bt,
                                                   __bf16* __restrict__ C) {
  __shared__ __attribute__((aligned(16))) __bf16 As[128 * 32];
  __shared__ __attribute__((aligned(16))) __bf16 Bs[128 * 32];
  const int m0 = blockIdx.y * 128;
  const int n0 = blockIdx.x * 128;
  const int wave = threadIdx.x >> 6;
  const int lane = threadIdx.x & 63;
  const int quad = lane >> 4;
  const int l16 = lane & 15;
  const int wm = (wave >> 1) * 64;
  const int wn = (wave & 1) * 64;

  floatx4 acc[4][4] = {};

  for (int k0 = 0; k0 < GK; k0 += 32) {
#pragma unroll
    for (int q = 0; q < 2; ++q) {
      int h = (wave * 2 + q) * 64 + lane;  // chunk id 0..511 (16B chunks)
      int r = h >> 2;                      // tile row (4 chunks/row)
      int cg = (h & 3) ^ ((r >> 1) & 3);   // swizzled global chunk col
      const __bf16* srcA = A + (size_t)(m0 + r) * GK + k0 + cg * 8;
      const __bf16* srcB = Bt + (size_t)(n0 + r) * GK + k0 + cg * 8;
      __builtin_amdgcn_global_load_lds(
          (const __attribute__((address_space(1))) void*)srcA,
          (__attribute__((address_space(3))) void*)(As + (wave * 2 + q) * 512),
          16, 0, 0);
      __builtin_amdgcn_global_load_lds(
          (const __attribute__((address_space(1))) void*)srcB,
          (__attribute__((address_space(3))) void*)(Bs + (wave * 2 + q) * 512),
          16, 0, 0);
    }
    __syncthreads();

    bf16x8 af[4], bfr[4];
#pragma unroll
    for (int t = 0; t < 4; ++t) {
      int m = wm + t * 16 + l16;
      int cA = quad ^ ((m >> 1) & 3);
      af[t] = *(const bf16x8*)(As + m * 32 + cA * 8);
      int n = wn + t * 16 + l16;
      int cB = quad ^ ((n >> 1) & 3);
      bfr[t] = *(const bf16x8*)(Bs + n * 32 + cB * 8);
    }
#pragma unroll
    for (int tm = 0; tm < 4; ++tm)
#pragma unroll
      for (int tn = 0; tn < 4; ++tn)
        acc[tm][tn] = __builtin_amdgcn_mfma_f32_16x16x32_bf16(
            af[tm], bfr[tn], acc[tm][tn], 0, 0, 0);
    __syncthreads();
  }

  // epilogue: C/D layout col=lane&15, row=quad*4+reg (m89-verified)
#pragma unroll
  for (int tm = 0; tm < 4; ++tm)
#pragma unroll
    for (int tn = 0; tn < 4; ++tn)
#pragma unroll
      for (int i = 0; i < 4; ++i) {
        int m = m0 + wm + tm * 16 + quad * 4 + i;
        int n = n0 + wn + tn * 16 + l16;
        C[(size_t)m * GN + n] = (__bf16)acc[tm][tn][i];
      }
}

// ---- fused SRU scan: 16384 channels, chunk-8 double-buffered prefetch --------
#define LOAD_CHUNK(tb, U0, U1, U2, X)             \
  _Pragma("unroll") for (int i = 0; i < 8; ++i) { \
    size_t o = (size_t)((tb) + i) * 49152;        \
    U0[i] = up[o];                                \
    U1[i] = up[o + 512];                          \
    U2[i] = up[o + 1024];                         \
    X[i] = xp[(size_t)((tb) + i) * 16384];        \
  }

#define COMPUTE_CHUNK(tb, U0, U1, U2, X)                           \
  _Pragma("unroll") for (int i = 0; i < 8; ++i) {                  \
    float u0 = (float)U0[i], u1 = (float)U1[i], u2 = (float)U2[i]; \
    float a1 = __builtin_fmaf(vf, c, u1 + bfv);                    \
    float f = __builtin_amdgcn_rcpf(1.f + __expf(-a1));            \
    c = __builtin_fmaf(f, c - u0, u0);                             \
    float a2 = __builtin_fmaf(vr, c, u2 + brv);                    \
    float r = __builtin_amdgcn_rcpf(1.f + __expf(-a2));            \
    float tt = __expf(-2.f * __builtin_fabsf(c));                  \
    float g = (1.f - tt) * __builtin_amdgcn_rcpf(1.f + tt);        \
    g = __builtin_copysignf(g, c);                                 \
    float xs = X[i] * 1.7320508075688772f;                         \
    float h = __builtin_fmaf(r, g - xs, xs);                       \
    out[(size_t)((tb) + i) * 16384 + tid] = h;                     \
  }

__global__ __launch_bounds__(64, 1) void scan_kernel(
    const __bf16* __restrict__ u, const float* __restrict__ x,
    const float* __restrict__ wc, const float* __restrict__ bias,
    const float* __restrict__ c0, float* __restrict__ out) {
  const int tid = blockIdx.x * 64 + threadIdx.x;  // 0..16383 = b*512+j
  const int j = tid & 511;
  const float vf = wc[j], vr = wc[512 + j];
  const float bfv = bias[j], brv = bias[512 + j];
  float c = c0[tid];
  const __bf16* up = u + (size_t)(tid >> 9) * 1536 + j;  // + t*49152 + gate*512
  const float* xp = x + tid;                             // + t*16384

  __bf16 u0A[8], u1A[8], u2A[8];
  __bf16 u0B[8], u1B[8], u2B[8];
  float xA[8], xB[8];

  LOAD_CHUNK(0, u0A, u1A, u2A, xA);
  for (int tc = 0; tc < 128; tc += 2) {
    LOAD_CHUNK((tc + 1) * 8, u0B, u1B, u2B, xB);
    COMPUTE_CHUNK(tc * 8, u0A, u1A, u2A, xA);
    if (tc + 2 < 128) LOAD_CHUNK((tc + 2) * 8, u0A, u1A, u2A, xA);
    COMPUTE_CHUNK((tc + 1) * 8, u0B, u1B, u2B, xB);
  }
  out[(size_t)16777216 + tid] = c;  // c_last
}

extern "C" void kernel_launch(void* const* d_in, const int* in_sizes, int n_in,
                              void* d_out, int out_size, void* d_ws, size_t ws_size,
                              hipStream_t stream) {
  const float* x = (const float*)d_in[0];     // (1024,32,512) fp32
  const float* w = (const float*)d_in[1];     // (512,1536)    fp32
  const float* wc = (const float*)d_in[2];    // (1024,)       fp32
  const float* bias = (const float*)d_in[3];  // (1024,)       fp32
  const float* c0 = (const float*)d_in[4];    // (32,512)      fp32
  float* out = (float*)d_out;                 // h (L,B,d) fp32 | c_last (B,d) fp32

  char* ws = (char*)d_ws;
  __bf16* xb = (__bf16*)ws;                        // 33,554,432 B
  __bf16* wt = (__bf16*)(ws + 33554432);           //  1,572,864 B
  __bf16* u = (__bf16*)(ws + 33554432 + 1572864);  // 100,663,296 B

  cvt_x<<<16384, 256, 0, stream>>>((const float4*)x, (bf16x4*)xb);
  cvt_w<<<3072, 256, 0, stream>>>(w, wt);
  dim3 gg(12, 256);
  gemm_kernel<<<gg, 256, 0, stream>>>(xb, wt, u);
  scan_kernel<<<256, 64, 0, stream>>>(u, x, wc, bias, c0, out);
}

// Round 4
// 324.897 us; speedup vs baseline: 1.1221x; 1.1221x over previous
//
#include <hip/hip_runtime.h>
#include <hip/hip_bf16.h>

// SRU cell, fp32 in / fp32 out (internal bf16 MFMA GEMM).
// u = x@W; then L-sequential scan parallel over B*d.
// L=1024, B=32, d=512. M=32768, K=512, N=1536.
// ws: Wt (bf16 [N][K], 1.5MB) | u (bf16 [M][N], 96MB)

typedef __attribute__((ext_vector_type(8))) __bf16 bf16x8;
typedef __attribute__((ext_vector_type(4))) __bf16 bf16x4;
typedef __attribute__((ext_vector_type(4))) float floatx4;

#define GK 512
#define GN 1536

// ---- convert + transpose weight: W[K][N] fp32 -> Wt[N][K] bf16 ---------------
__global__ __launch_bounds__(256) void cvt_w(const float* __restrict__ w,
                                             __bf16* __restrict__ wt) {
  int idx = blockIdx.x * 256 + threadIdx.x;  // 0..786431 = n*512+k
  int n = idx >> 9, k = idx & 511;
  wt[idx] = (__bf16)w[(size_t)k * GN + n];
}

// ---- GEMM: C[M][N] = A_f32[M][K] * Wt[N][K]^T, bf16 MFMA, bf16 out -----------
// 128x128 tile, BK=64 (8 K-iters). A: fp32 global -> reg cvt -> swizzled LDS
// (folds the x->bf16 conversion pass into the GEMM). B: async global_load_lds
// w/ per-lane swizzled source. XOR swizzle (chunk ^= row&7) keeps all
// ds_read_b128 at 2-way bank aliasing (free per m136).
__global__ __launch_bounds__(256, 2) void gemm_kernel(const float* __restrict__ A,
                                                      const __bf16* __restrict__ Bt,
                                                      __bf16* __restrict__ C) {
  __shared__ __attribute__((aligned(16))) __bf16 As[128 * 64];
  __shared__ __attribute__((aligned(16))) __bf16 Bs[128 * 64];
  const int m0 = blockIdx.y * 128;
  const int n0 = blockIdx.x * 128;
  const int t = threadIdx.x;
  const int wave = t >> 6, lane = t & 63;
  const int quad = lane >> 4, l16 = lane & 15;
  const int wm = (wave >> 1) * 64, wn = (wave & 1) * 64;

  floatx4 acc[4][4] = {};

  const int ar = t >> 4;         // row group index (0..15)
  const int ak = (t & 15) * 4;   // k element offset within BK
  const int ac = (t & 15) >> 1;  // 16B-chunk within row
  const int ah = t & 1;          // 8B half within chunk
  float4 areg[8];

  // prologue: A loads for k0 = 0 (coalesced: instr q covers rows q*16..q*16+15)
#pragma unroll
  for (int q = 0; q < 8; ++q)
    areg[q] = *(const float4*)(A + (size_t)(m0 + q * 16 + ar) * GK + ak);

  for (int kk = 0; kk < 8; ++kk) {
    const int k0 = kk * 64;
    // B async staging: wave covers rows wave*32..+32, 4 rounds of 8 rows
#pragma unroll
    for (int q = 0; q < 4; ++q) {
      int rb = wave * 4 + q;
      int n = rb * 8 + (lane >> 3);
      int c = lane & 7;
      const __bf16* src = Bt + (size_t)(n0 + n) * GK + k0 + ((c ^ (n & 7)) * 8);
      __builtin_amdgcn_global_load_lds(
          (const __attribute__((address_space(1))) void*)src,
          (__attribute__((address_space(3))) void*)(Bs + rb * 512), 16, 0, 0);
    }
    // A: convert prefetched regs -> swizzled LDS
#pragma unroll
    for (int q = 0; q < 8; ++q) {
      int r = q * 16 + ar;
      float4 v = areg[q];
      bf16x4 o = {(__bf16)v.x, (__bf16)v.y, (__bf16)v.z, (__bf16)v.w};
      *(bf16x4*)(As + r * 64 + (ac ^ (r & 7)) * 8 + ah * 4) = o;
    }
    __syncthreads();
    // software-prefetch A for next iter (drains at end-of-iter barrier)
    if (kk < 7) {
#pragma unroll
      for (int q = 0; q < 8; ++q)
        areg[q] = *(const float4*)(A + (size_t)(m0 + q * 16 + ar) * GK + k0 + 64 + ak);
    }
    // compute: 2 k-windows of 32
#pragma unroll
    for (int ks = 0; ks < 2; ++ks) {
      bf16x8 af[4], bfr[4];
#pragma unroll
      for (int tt = 0; tt < 4; ++tt) {
        int m = wm + tt * 16 + l16;
        af[tt] = *(const bf16x8*)(As + m * 64 + (((ks * 4 + quad) ^ (m & 7)) * 8));
        int n = wn + tt * 16 + l16;
        bfr[tt] = *(const bf16x8*)(Bs + n * 64 + (((ks * 4 + quad) ^ (n & 7)) * 8));
      }
#pragma unroll
      for (int tm = 0; tm < 4; ++tm)
#pragma unroll
        for (int tn = 0; tn < 4; ++tn)
          acc[tm][tn] = __builtin_amdgcn_mfma_f32_16x16x32_bf16(
              af[tm], bfr[tn], acc[tm][tn], 0, 0, 0);
    }
    __syncthreads();
  }

  // epilogue: C/D layout col=lane&15, row=quad*4+reg (m89-verified)
#pragma unroll
  for (int tm = 0; tm < 4; ++tm)
#pragma unroll
    for (int tn = 0; tn < 4; ++tn)
#pragma unroll
      for (int i = 0; i < 4; ++i) {
        int m = m0 + wm + tm * 16 + quad * 4 + i;
        int n = n0 + wn + tn * 16 + l16;
        C[(size_t)m * GN + n] = (__bf16)acc[tm][tn][i];
      }
}

// ---- SRU scan: producer/consumer wave pipeline -------------------------------
// 256 blocks x 128 thr. Block g owns 64 channels: b=g>>3 (fixed), j=j0+lane.
// Wave1 prefetches 16-step stages (u: 48x128B segments, x: 16x256B) into a
// 2-deep LDS ring via global_load_lds (per-lane global addr, uniform LDS base);
// wave0 computes from LDS. __syncthreads per stage = vmcnt drain -> data ready.
__global__ __launch_bounds__(128, 1) void scan_kernel(
    const __bf16* __restrict__ u, const float* __restrict__ x,
    const float* __restrict__ wc, const float* __restrict__ bias,
    const float* __restrict__ c0, float* __restrict__ out) {
  __shared__ __attribute__((aligned(16))) unsigned char ring[2][10240];
  const int g = blockIdx.x;
  const int b = g >> 3;
  const int j0 = (g & 7) * 64;
  const int wave = threadIdx.x >> 6;
  const int lane = threadIdx.x & 63;
  const int ob = b * 512 + j0 + lane;  // this lane's channel (consumer)

  if (wave == 1) {
    // producer: per-lane time-invariant element offsets
    int pre_u[6], pre_x[4];
#pragma unroll
    for (int r = 0; r < 6; ++r) {
      int seg = r * 8 + (lane >> 3);  // seg = i*3 + q
      int i = seg / 3;
      int q = seg - i * 3;
      pre_u[r] = i * 49152 + b * 1536 + q * 512 + j0 + (lane & 7) * 8;
    }
#pragma unroll
    for (int r = 0; r < 4; ++r) {
      int i = r * 4 + (lane >> 4);
      pre_x[r] = i * 16384 + b * 512 + j0 + (lane & 15) * 4;
    }
    // prologue: stage 0
    {
      unsigned char* base = ring[0];
#pragma unroll
      for (int r = 0; r < 6; ++r)
        __builtin_amdgcn_global_load_lds(
            (const __attribute__((address_space(1))) void*)(u + pre_u[r]),
            (__attribute__((address_space(3))) void*)(base + r * 1024), 16, 0, 0);
#pragma unroll
      for (int r = 0; r < 4; ++r)
        __builtin_amdgcn_global_load_lds(
            (const __attribute__((address_space(1))) void*)(x + pre_x[r]),
            (__attribute__((address_space(3))) void*)(base + 6144 + r * 1024), 16, 0, 0);
    }
    __syncthreads();
    for (int s = 0; s < 64; ++s) {
      if (s + 1 < 64) {
        unsigned char* base = ring[(s + 1) & 1];
        size_t tu = (size_t)(s + 1) * 16 * 49152;
        size_t tx = (size_t)(s + 1) * 16 * 16384;
#pragma unroll
        for (int r = 0; r < 6; ++r)
          __builtin_amdgcn_global_load_lds(
              (const __attribute__((address_space(1))) void*)(u + tu + pre_u[r]),
              (__attribute__((address_space(3))) void*)(base + r * 1024), 16, 0, 0);
#pragma unroll
        for (int r = 0; r < 4; ++r)
          __builtin_amdgcn_global_load_lds(
              (const __attribute__((address_space(1))) void*)(x + tx + pre_x[r]),
              (__attribute__((address_space(3))) void*)(base + 6144 + r * 1024), 16, 0, 0);
      }
      __syncthreads();
    }
  } else {
    // consumer
    const float vf = wc[j0 + lane], vr = wc[512 + j0 + lane];
    const float bfv = bias[j0 + lane], brv = bias[512 + j0 + lane];
    float c = c0[ob];
    __syncthreads();  // matches producer prologue barrier
    for (int s = 0; s < 64; ++s) {
      const unsigned char* base = ring[s & 1];
#pragma unroll
      for (int i = 0; i < 16; ++i) {
        float u0 = (float)*(const __bf16*)(base + i * 384 + lane * 2);
        float u1 = (float)*(const __bf16*)(base + i * 384 + 128 + lane * 2);
        float u2 = (float)*(const __bf16*)(base + i * 384 + 256 + lane * 2);
        float xv = *(const float*)(base + 6144 + i * 256 + lane * 4);
        float a1 = __builtin_fmaf(vf, c, u1 + bfv);
        float f = __builtin_amdgcn_rcpf(1.f + __expf(-a1));
        c = __builtin_fmaf(f, c - u0, u0);
        float a2 = __builtin_fmaf(vr, c, u2 + brv);
        float r = __builtin_amdgcn_rcpf(1.f + __expf(-a2));
        float tt = __expf(-2.f * __builtin_fabsf(c));
        float gg = (1.f - tt) * __builtin_amdgcn_rcpf(1.f + tt);
        gg = __builtin_copysignf(gg, c);
        float xs = xv * 1.7320508075688772f;
        float h = __builtin_fmaf(r, gg - xs, xs);
        out[(size_t)(s * 16 + i) * 16384 + ob] = h;
      }
      __syncthreads();
    }
    out[(size_t)16777216 + ob] = c;  // c_last
  }
}

extern "C" void kernel_launch(void* const* d_in, const int* in_sizes, int n_in,
                              void* d_out, int out_size, void* d_ws, size_t ws_size,
                              hipStream_t stream) {
  const float* x = (const float*)d_in[0];     // (1024,32,512) fp32
  const float* w = (const float*)d_in[1];     // (512,1536)    fp32
  const float* wc = (const float*)d_in[2];    // (1024,)       fp32
  const float* bias = (const float*)d_in[3];  // (1024,)       fp32
  const float* c0 = (const float*)d_in[4];    // (32,512)      fp32
  float* out = (float*)d_out;                 // h (L,B,d) | c_last (B,d)

  char* ws = (char*)d_ws;
  __bf16* wt = (__bf16*)ws;             // 1,572,864 B
  __bf16* u = (__bf16*)(ws + 1572864);  // 100,663,296 B

  cvt_w<<<3072, 256, 0, stream>>>(w, wt);
  dim3 gg(12, 256);
  gemm_kernel<<<gg, 256, 0, stream>>>(x, wt, u);
  scan_kernel<<<256, 128, 0, stream>>>(u, x, wc, bias, c0, out);
}